// Round 12
// baseline (564.886 us; speedup 1.0000x reference)
//
#include <hip/hip_runtime.h>

#define N_NODES   100000
#define N_EDGES   1600000
#define F_IN      10
#define HD        128
#define N_LAYERS  3
#define N_GRAPHS  256
#define N_CLASSES 25
#define BN_EPS    1e-5f
#define APITCH    136   // LDS pitch (shorts): 272 B rows -> 4-bank step, 2-way conflict max (free)

#define NBUCK     196   // ceil(100000/512) row buckets (row >> 9)
#define SCAT_TILE 4096  // edges per k_scatter/hist block
#define BUCK_CAP  16384 // LDS stage cap per bucket
#define PREPW_BLKS ((N_LAYERS*HD*HD)/256)   // 192
#define NTILE     ((N_NODES + 63)/64)       // 1563 row tiles

typedef __attribute__((ext_vector_type(8))) short bf8;
typedef __attribute__((ext_vector_type(4))) float f32x4;

static __device__ __forceinline__ unsigned short f2bf(float f){
    unsigned u = __float_as_uint(f);
    unsigned r = (u + 0x7fffu + ((u >> 16) & 1u)) >> 16;
    return (unsigned short)r;
}
static __device__ __forceinline__ float bflo(unsigned u){ return __uint_as_float(u << 16); }
static __device__ __forceinline__ float bfhi(unsigned u){ return __uint_as_float(u & 0xffff0000u); }
static __device__ __forceinline__ unsigned packbf(float a, float b){
    return (unsigned)f2bf(a) | ((unsigned)f2bf(b) << 16);
}

// ---------------- k_pre: WT transpose (blocks [0,192)) + bucket histogram ----------------
__global__ __launch_bounds__(256) void k_pre(const float* __restrict__ Wc,
        unsigned short* __restrict__ WT, const int* __restrict__ rows,
        int* __restrict__ gcount, int e){
    __shared__ int lhist[NBUCK];
    int t = threadIdx.x;
    if (blockIdx.x < PREPW_BLKS){
        int i = blockIdx.x*256 + t;                // over L*128*128
        int l = i >> 14;
        int r = (i >> 7) & 127;                    // k
        int c = i & 127;                           // n
        WT[(l << 14) + c*HD + r] = f2bf(Wc[i]);
        return;
    }
    int bid = blockIdx.x - PREPW_BLKS;
    if (t < NBUCK) lhist[t] = 0;
    __syncthreads();
    int i0 = bid*SCAT_TILE + t;
    #pragma unroll
    for (int k = 0; k < 16; k++){
        int i = i0 + k*256;
        if (i < e) atomicAdd(&lhist[rows[i] >> 9], 1);
    }
    __syncthreads();
    if (t < NBUCK && lhist[t] > 0) atomicAdd(&gcount[t], lhist[t]);
}

// ---------------- k_scatter: in-block gcount scan + bucketed counting sort ----------------
__global__ __launch_bounds__(256) void k_scatter(const int* __restrict__ rows,
        const int* __restrict__ cols, const int* __restrict__ gcount,
        int* __restrict__ gcur, unsigned* __restrict__ ebuf, int e){
    __shared__ int lbase[NBUCK];
    __shared__ int lcur[NBUCK];
    __shared__ int gbase[NBUCK];
    __shared__ int sbuf[256];
    __shared__ unsigned sedge[SCAT_TILE];
    __shared__ unsigned char sbuck[SCAT_TILE];
    int t = threadIdx.x;
    // scan gcount -> bucket base (replaces the k_scanb dispatch)
    int gval = (t < NBUCK) ? gcount[t] : 0;
    sbuf[t] = gval;
    __syncthreads();
    for (int d = 1; d < 256; d <<= 1){
        int tv = (t >= d) ? sbuf[t-d] : 0;
        __syncthreads();
        sbuf[t] += tv;
        __syncthreads();
    }
    int bucket_base = sbuf[t] - gval;
    __syncthreads();
    int i0 = blockIdx.x*SCAT_TILE + t;
    int r[16], c[16];
    if (t < NBUCK) lcur[t] = 0;
    __syncthreads();
    #pragma unroll
    for (int k = 0; k < 16; k++){
        int i = i0 + k*256;
        if (i < e){
            r[k] = rows[i]; c[k] = cols[i];
            atomicAdd(&lcur[r[k] >> 9], 1);
        } else r[k] = -1;
    }
    __syncthreads();
    int myc = (t < NBUCK) ? lcur[t] : 0;
    sbuf[t] = myc;
    __syncthreads();
    for (int d = 1; d < 256; d <<= 1){
        int tv = (t >= d) ? sbuf[t-d] : 0;
        __syncthreads();
        sbuf[t] += tv;
        __syncthreads();
    }
    if (t < NBUCK){
        lbase[t] = sbuf[t] - myc;
        lcur[t]  = sbuf[t] - myc;
        if (myc > 0) gbase[t] = bucket_base + atomicAdd(&gcur[t], myc);
    }
    __syncthreads();
    #pragma unroll
    for (int k = 0; k < 16; k++){
        if (r[k] >= 0){
            int bk = r[k] >> 9;
            int off = atomicAdd(&lcur[bk], 1);
            sedge[off] = ((unsigned)(r[k] & 511) << 17) | (unsigned)c[k];
            sbuck[off] = (unsigned char)bk;
        }
    }
    __syncthreads();
    int tot = sbuf[255];
    for (int i = t; i < tot; i += 256){
        int bk = sbuck[i];
        ebuf[gbase[bk] + (i - lbase[bk])] = sedge[i];
    }
}

// ---------------- k_build: in-block gcount scan -> rowptr, dinv, coalesced colidx ----------------
__global__ __launch_bounds__(512) void k_build(const unsigned* __restrict__ ebuf,
        const int* __restrict__ gcount, int* __restrict__ rowptr,
        float* __restrict__ dinv, int* __restrict__ colidx, int n, int etot){
    __shared__ int hist[512];
    __shared__ int cur[512];
    __shared__ int colstage[BUCK_CAP];
    __shared__ int sscan[256];
    int t = threadIdx.x;
    int gval = (t < NBUCK) ? gcount[t] : 0;
    if (t < 256) sscan[t] = gval;
    __syncthreads();
    for (int d = 1; d < 256; d <<= 1){
        int tv = (t < 256 && t >= d) ? sscan[t-d] : 0;
        __syncthreads();
        if (t < 256) sscan[t] += tv;
        __syncthreads();
    }
    int b = blockIdx.x;
    int e_ = sscan[b];
    int s  = e_ - gcount[b];
    int cnt = e_ - s;
    int row0 = b << 9;
    int nrows = min(512, n - row0);
    if (b == 0 && t == 0) rowptr[n] = etot;
    hist[t] = 0;
    __syncthreads();
    for (int i = t; i < cnt; i += 512)
        atomicAdd(&hist[ebuf[s + i] >> 17], 1);
    __syncthreads();
    int myc = hist[t];
    cur[t] = myc;
    __syncthreads();
    for (int d = 1; d < 512; d <<= 1){
        int tv = (t >= d) ? cur[t-d] : 0;
        __syncthreads();
        cur[t] += tv;
        __syncthreads();
    }
    int excl = cur[t] - myc;
    if (t < nrows){
        rowptr[row0 + t] = s + excl;
        dinv[row0 + t] = rsqrtf((float)(myc + 1));   // +1 self loop
    }
    cur[t] = excl;
    __syncthreads();
    for (int i = t; i < cnt; i += 512){
        unsigned v = ebuf[s + i];
        int off = atomicAdd(&cur[v >> 17], 1);
        colstage[off] = (int)(v & 0x1ffffu);
    }
    __syncthreads();
    for (int i = t; i < cnt; i += 512)
        colidx[s + i] = colstage[i];
}

// ---------------- shared gemm body: As(64 rows) @ Bs -> hw, dinv epilogue ----------------
// wave = 16 rows x 128 cols; 32 MFMA 16x16x32; epilogue stages C through retired
// As region and writes coalesced uint4. Same math/rounding as R11 -> bit-identical.
static __device__ __forceinline__ void gemm_tile(unsigned short* As, unsigned short* Bs,
        const unsigned short* __restrict__ WT, const float* __restrict__ dinv,
        unsigned short* __restrict__ hw, int row0, int n, int tid){
    const uint4* w4 = (const uint4*)WT;
    #pragma unroll
    for (int q = tid; q < 2048; q += 256){                 // stage B: 128 rows x 16 chunks
        int r = q >> 4, c = q & 15;
        *(uint4*)&Bs[r*APITCH + c*8] = w4[r*16 + c];
    }
    __syncthreads();

    int w = tid >> 6, lane = tid & 63;
    int l15 = lane & 15, quad = lane >> 4;
    f32x4 acc[8];
    #pragma unroll
    for (int ct = 0; ct < 8; ct++) acc[ct] = (f32x4){0.f,0.f,0.f,0.f};

    int arow = w*16 + l15;
    #pragma unroll
    for (int kc = 0; kc < 4; kc++){
        int ko = kc*32 + quad*8;
        bf8 a = *(const bf8*)&As[arow*APITCH + ko];
        #pragma unroll
        for (int ct = 0; ct < 8; ct++){
            bf8 b = *(const bf8*)&Bs[(ct*16 + l15)*APITCH + ko];
            acc[ct] = __builtin_amdgcn_mfma_f32_16x16x32_bf16(a, b, acc[ct], 0, 0, 0);
        }
    }
    __syncthreads();                                       // done reading As

    #pragma unroll
    for (int reg = 0; reg < 4; reg++){
        int rloc = w*16 + quad*4 + reg;
        int grow = row0 + rloc;
        float dv = (grow < n) ? dinv[grow] : 0.f;
        #pragma unroll
        for (int ct = 0; ct < 8; ct++)
            As[rloc*APITCH + ct*16 + l15] = f2bf(acc[ct][reg] * dv);
    }
    __syncthreads();

    #pragma unroll
    for (int q = tid; q < 1024; q += 256){                 // coalesced uint4 store-out
        int r = q >> 4, c = q & 15;
        if (row0 + r < n)
            *(uint4*)&hw[(size_t)(row0 + r)*HD + c*8] = *(const uint4*)&As[r*APITCH + c*8];
    }
}

// ---------------- shared agg body: gather+BN+relu for one node -> packed dword ----------------
static __device__ __forceinline__ unsigned agg_node(const unsigned* __restrict__ hwp,
        const int* __restrict__ rowptr, const int* __restrict__ colidx,
        const float* __restrict__ dinv, int node, int lane,
        float2 cb, float2 cm, float2 cv, float2 cg, float2 cbe){
    unsigned self = hwp[(size_t)node*64 + lane];
    float ax = bflo(self), ay = bfhi(self);
    float bx = 0.f, by = 0.f;
    int s = rowptr[node], e = rowptr[node+1];
    int t = s;
    for (; t + 8 <= e; t += 8){
        int c0 = colidx[t],   c1 = colidx[t+1];
        int c2 = colidx[t+2], c3 = colidx[t+3];
        int c4 = colidx[t+4], c5 = colidx[t+5];
        int c6 = colidx[t+6], c7 = colidx[t+7];
        unsigned v0 = hwp[(size_t)c0*64 + lane];
        unsigned v1 = hwp[(size_t)c1*64 + lane];
        unsigned v2 = hwp[(size_t)c2*64 + lane];
        unsigned v3 = hwp[(size_t)c3*64 + lane];
        unsigned v4 = hwp[(size_t)c4*64 + lane];
        unsigned v5 = hwp[(size_t)c5*64 + lane];
        unsigned v6 = hwp[(size_t)c6*64 + lane];
        unsigned v7 = hwp[(size_t)c7*64 + lane];
        ax += bflo(v0); ay += bfhi(v0);
        bx += bflo(v1); by += bfhi(v1);
        ax += bflo(v2); ay += bfhi(v2);
        bx += bflo(v3); by += bfhi(v3);
        ax += bflo(v4); ay += bfhi(v4);
        bx += bflo(v5); by += bfhi(v5);
        ax += bflo(v6); ay += bfhi(v6);
        bx += bflo(v7); by += bfhi(v7);
    }
    for (; t + 4 <= e; t += 4){
        int c0 = colidx[t],   c1 = colidx[t+1];
        int c2 = colidx[t+2], c3 = colidx[t+3];
        unsigned v0 = hwp[(size_t)c0*64 + lane];
        unsigned v1 = hwp[(size_t)c1*64 + lane];
        unsigned v2 = hwp[(size_t)c2*64 + lane];
        unsigned v3 = hwp[(size_t)c3*64 + lane];
        ax += bflo(v0); ay += bfhi(v0);
        bx += bflo(v1); by += bfhi(v1);
        ax += bflo(v2); ay += bfhi(v2);
        bx += bflo(v3); by += bfhi(v3);
    }
    for (; t < e; t++){
        unsigned v = hwp[(size_t)colidx[t]*64 + lane];
        ax += bflo(v); ay += bfhi(v);
    }
    ax += bx; ay += by;
    float dv = dinv[node];
    float rx = (ax*dv + cb.x - cm.x) * rsqrtf(cv.x + BN_EPS) * cg.x + cbe.x;
    float ry = (ay*dv + cb.y - cm.y) * rsqrtf(cv.y + BN_EPS) * cg.y + cbe.y;
    return packbf(fmaxf(rx, 0.f), fmaxf(ry, 0.f));
}

// ---------------- K1: proj (h0 in LDS only) + gemm0 -> hw ----------------
__global__ __launch_bounds__(256) void k_layer0(const float* __restrict__ x,
        const float* __restrict__ Wp, const float* __restrict__ bp,
        const unsigned short* __restrict__ WT, const float* __restrict__ dinv,
        unsigned short* __restrict__ hw, int n){
    extern __shared__ char smem[];
    unsigned short* As = (unsigned short*)smem;            // 64 x APITCH
    unsigned short* Bs = As + 64*APITCH;                   // 128 x APITCH
    unsigned* As32 = (unsigned*)As;
    int tid = threadIdx.x;
    int row0 = blockIdx.x*64;

    float* sW = (float*)Bs;                                // Wp scratch (5.5 KB) in Bs region
    float* sb = sW + F_IN*HD;
    for (int t = tid; t < F_IN*HD; t += 256) sW[t] = Wp[t];
    if (tid < HD) sb[tid] = bp[tid];
    __syncthreads();

    int j = tid & 63, ln = tid >> 6;
    for (int r = ln; r < 64; r += 4){
        int node = row0 + r;
        unsigned val = 0u;
        if (node < n){
            float a0 = sb[2*j], a1 = sb[2*j+1];
            #pragma unroll
            for (int k = 0; k < F_IN; k++){
                float xv = x[(size_t)node*F_IN + k];
                a0 += xv * sW[k*HD + 2*j];
                a1 += xv * sW[k*HD + 2*j+1];
            }
            val = packbf(fmaxf(a0, 0.f), fmaxf(a1, 0.f));
        }
        As32[r*68 + j] = val;                              // h0 row -> LDS (never global)
    }
    __syncthreads();
    gemm_tile(As, Bs, WT, dinv, hw, row0, n, tid);
}

// ---------------- K2/K3: agg(layer l) + gemm(l+1), h in LDS only ----------------
__global__ __launch_bounds__(256) void k_layerF(const unsigned* __restrict__ hwp,
        const int* __restrict__ rowptr, const int* __restrict__ colidx,
        const float* __restrict__ dinv, const float* __restrict__ bc,
        const float* __restrict__ bmean, const float* __restrict__ bvar,
        const float* __restrict__ bgamma, const float* __restrict__ bbeta,
        const unsigned short* __restrict__ WT, unsigned short* __restrict__ hwout, int n){
    extern __shared__ char smem[];
    unsigned short* As = (unsigned short*)smem;
    unsigned short* Bs = As + 64*APITCH;
    unsigned* As32 = (unsigned*)As;
    int tid = threadIdx.x;
    int w = tid >> 6, lane = tid & 63;
    int row0 = blockIdx.x*64;

    float2 cb  = ((const float2*)bc)[lane];
    float2 cm  = ((const float2*)bmean)[lane];
    float2 cv  = ((const float2*)bvar)[lane];
    float2 cg  = ((const float2*)bgamma)[lane];
    float2 cbe = ((const float2*)bbeta)[lane];

    for (int i = 0; i < 16; i++){
        int vloc = w*16 + i;
        int node = row0 + vloc;
        unsigned val = 0u;
        if (node < n)
            val = agg_node(hwp, rowptr, colidx, dinv, node, lane, cb, cm, cv, cg, cbe);
        As32[vloc*68 + lane] = val;                        // h row -> LDS (never global)
    }
    __syncthreads();
    gemm_tile(As, Bs, WT, dinv, hwout, row0, n, tid);
}

// ---------------- K4: agg(layer 2) + pool (h3 in LDS only) ----------------
// pool tile boundaries = 64*blockIdx, identical to the old k_pool segmentation.
__global__ __launch_bounds__(256) void k_layerP(const unsigned* __restrict__ hwp,
        const int* __restrict__ rowptr, const int* __restrict__ colidx,
        const float* __restrict__ dinv, const float* __restrict__ bc,
        const float* __restrict__ bmean, const float* __restrict__ bvar,
        const float* __restrict__ bgamma, const float* __restrict__ bbeta,
        const int* __restrict__ batch, float* __restrict__ gsum,
        int* __restrict__ gmax, int n){
    extern __shared__ char smem[];
    unsigned* As32 = (unsigned*)smem;                      // 64 x 68 dwords
    int tid = threadIdx.x;
    int w = tid >> 6, lane = tid & 63;
    int row0 = blockIdx.x*64;

    float2 cb  = ((const float2*)bc)[lane];
    float2 cm  = ((const float2*)bmean)[lane];
    float2 cv  = ((const float2*)bvar)[lane];
    float2 cg  = ((const float2*)bgamma)[lane];
    float2 cbe = ((const float2*)bbeta)[lane];

    for (int i = 0; i < 16; i++){
        int vloc = w*16 + i;
        int node = row0 + vloc;
        unsigned val = 0u;
        if (node < n)
            val = agg_node(hwp, rowptr, colidx, dinv, node, lane, cb, cm, cv, cg, cbe);
        As32[vloc*68 + lane] = val;
    }
    __syncthreads();
    if (tid < 64){                                         // one wave pools this tile
        int q = tid;
        int start = row0, end = min(row0 + 64, n);
        if (start < end){
            int cur = batch[start];
            float s0 = 0.f, s1 = 0.f, m0 = 0.f, m1 = 0.f;
            for (int i = start; i < end; i++){
                int b = batch[i];
                unsigned v = As32[(i - start)*68 + q];
                float v0 = bflo(v), v1 = bfhi(v);
                if (b != cur){
                    atomicAdd(&gsum[cur*HD + 2*q],     s0);
                    atomicAdd(&gsum[cur*HD + 2*q + 1], s1);
                    atomicMax(&gmax[cur*HD + 2*q],     __float_as_int(m0));
                    atomicMax(&gmax[cur*HD + 2*q + 1], __float_as_int(m1));
                    s0 = s1 = m0 = m1 = 0.f; cur = b;
                }
                s0 += v0; s1 += v1;
                m0 = fmaxf(m0, v0); m1 = fmaxf(m1, v1);
            }
            atomicAdd(&gsum[cur*HD + 2*q],     s0);
            atomicAdd(&gsum[cur*HD + 2*q + 1], s1);
            atomicMax(&gmax[cur*HD + 2*q],     __float_as_int(m0));
            atomicMax(&gmax[cur*HD + 2*q + 1], __float_as_int(m1));
        }
    }
}

// ---------------- fused head: count (binary search) + MLP1 + MLP2 ----------------
__global__ void k_head(const float* __restrict__ gsum, const int* __restrict__ gmax,
        const int* __restrict__ batch, const float* __restrict__ W1,
        const float* __restrict__ b1, const float* __restrict__ W2,
        const float* __restrict__ b2, float* __restrict__ out, int n){
    __shared__ float gv[2*HD];
    __shared__ float hid[HD];
    __shared__ int bound[2];
    int g = blockIdx.x, j = threadIdx.x;   // 128 threads
    if (j < 2){
        int target = g + j;
        int lo = 0, hi = n;
        while (lo < hi){ int mid = (lo + hi) >> 1; if (batch[mid] < target) lo = mid + 1; else hi = mid; }
        bound[j] = lo;
    }
    __syncthreads();
    float denom = (float)max(bound[1] - bound[0], 1);
    gv[j]    = gsum[g*HD+j] / denom;
    gv[HD+j] = __int_as_float(gmax[g*HD+j]);   // 0 for empty graphs (matches guard)
    __syncthreads();
    float acc = b1[j];
    #pragma unroll 8
    for (int k = 0; k < 2*HD; k++) acc += gv[k]*W1[k*HD + j];
    hid[j] = fmaxf(acc, 0.f);
    __syncthreads();
    if (j < N_CLASSES){
        float o = b2[j];
        #pragma unroll 4
        for (int k = 0; k < HD; k++) o += hid[k]*W2[k*N_CLASSES + j];
        out[g*N_CLASSES + j] = o;
    }
}

// ---------------- launch ----------------
extern "C" void kernel_launch(void* const* d_in, const int* in_sizes, int n_in,
                              void* d_out, int out_size, void* d_ws, size_t ws_size,
                              hipStream_t stream){
    const float* x   = (const float*)d_in[0];
    const int*  eidx = (const int*)d_in[1];
    const int* batch = (const int*)d_in[2];
    const float* Wp  = (const float*)d_in[3];
    const float* bp  = (const float*)d_in[4];
    const float* Wc  = (const float*)d_in[5];
    const float* bc  = (const float*)d_in[6];
    const float* bng = (const float*)d_in[7];
    const float* bnb = (const float*)d_in[8];
    const float* bnm = (const float*)d_in[9];
    const float* bnv = (const float*)d_in[10];
    const float* W1  = (const float*)d_in[11];
    const float* b1  = (const float*)d_in[12];
    const float* W2  = (const float*)d_in[13];
    const float* b2  = (const float*)d_in[14];
    float* out = (float*)d_out;

    // workspace (~65 MB). gcount|gcur|gsum|gmax contiguous -> one memset.
    char* ws = (char*)d_ws;
    size_t off = 0;
    unsigned short* hwA = (unsigned short*)(ws + off); off += (size_t)N_NODES*HD*2;    // 25.6 MB
    unsigned short* hwB = (unsigned short*)(ws + off); off += (size_t)N_NODES*HD*2;    // 25.6 MB
    unsigned short* WT  = (unsigned short*)(ws + off); off += (size_t)N_LAYERS*HD*HD*2;
    float* dinv   = (float*)(ws + off); off += (size_t)N_NODES*4;
    int*   rowptr = (int*)  (ws + off); off += (size_t)(N_NODES+16)*4;
    int*   colidx = (int*)  (ws + off); off += (size_t)N_EDGES*4;                      // 6.4 MB
    unsigned* ebuf= (unsigned*)(ws + off); off += (size_t)N_EDGES*4;                   // 6.4 MB
    int*   gcount = (int*)  (ws + off); off += 1024;                                   // zeroed region start
    int*   gcur   = (int*)  (ws + off); off += 1024;
    float* gsum   = (float*)(ws + off); off += (size_t)N_GRAPHS*HD*4;
    int*   gmax   = (int*)  (ws + off); off += (size_t)N_GRAPHS*HD*4;

    const int* rows = eidx;             // targets (aggregation index)
    const int* cols = eidx + N_EDGES;   // sources (gather index)

    hipMemsetAsync(gcount, 0, 2048 + (size_t)(N_GRAPHS*HD*2)*4, stream);

    int nsb = (N_EDGES + SCAT_TILE - 1)/SCAT_TILE;   // 391
    k_pre    <<<PREPW_BLKS + nsb, 256, 0, stream>>>(Wc, WT, rows, gcount, N_EDGES);
    k_scatter<<<nsb, 256, 0, stream>>>(rows, cols, gcount, gcur, ebuf, N_EDGES);
    k_build  <<<NBUCK, 512, 0, stream>>>(ebuf, gcount, rowptr, dinv, colidx, N_NODES, N_EDGES);

    size_t shmem = (size_t)(64 + 128)*APITCH*2;      // 52,224 B -> 3 blocks/CU
    size_t shmemP = (size_t)64*APITCH*2;             // 17,408 B (agg+pool only)
    k_layer0<<<NTILE, 256, shmem, stream>>>(x, Wp, bp, WT, dinv, hwA, N_NODES);
    k_layerF<<<NTILE, 256, shmem, stream>>>((const unsigned*)hwA, rowptr, colidx, dinv,
        bc, bnm, bnv, bng, bnb, WT + (size_t)1*HD*HD, hwB, N_NODES);
    k_layerF<<<NTILE, 256, shmem, stream>>>((const unsigned*)hwB, rowptr, colidx, dinv,
        bc + HD, bnm + HD, bnv + HD, bng + HD, bnb + HD, WT + (size_t)2*HD*HD, hwA, N_NODES);
    k_layerP<<<NTILE, 256, shmemP, stream>>>((const unsigned*)hwA, rowptr, colidx, dinv,
        bc + 2*HD, bnm + 2*HD, bnv + 2*HD, bng + 2*HD, bnb + 2*HD,
        batch, gsum, gmax, N_NODES);

    k_head<<<N_GRAPHS, 128, 0, stream>>>(gsum, gmax, batch, W1, b1, W2, b2, out, N_NODES);
}

// Round 13
// 420.855 us; speedup vs baseline: 1.3422x; 1.3422x over previous
//
#include <hip/hip_runtime.h>

#define N_NODES   100000
#define N_EDGES   1600000
#define F_IN      10
#define HD        128
#define N_LAYERS  3
#define N_GRAPHS  256
#define N_CLASSES 25
#define BN_EPS    1e-5f
#define POOL_TILE 64
#define LDS_PITCH 152   // A/B-stage pitch (shorts): 304 B rows, 16B-aligned, 2-way conflict max
#define CPITCH    136   // C-stage pitch (shorts)

#define NBUCK     196   // ceil(100000/512) row buckets (row >> 9)
#define SCAT_TILE 4096  // edges per scatter block
#define BCAP      9216  // padded bucket capacity (mean 8192, sd ~90 -> +11 sigma)
#define BUCK_CAP  16384 // LDS colstage cap per bucket
#define PREPW_BLKS ((N_LAYERS*HD*HD)/256)   // 192
#define PROJ_BLKS 1024

typedef __attribute__((ext_vector_type(8))) short bf8;
typedef __attribute__((ext_vector_type(4))) float f32x4;

static __device__ __forceinline__ unsigned short f2bf(float f){
    unsigned u = __float_as_uint(f);
    unsigned r = (u + 0x7fffu + ((u >> 16) & 1u)) >> 16;
    return (unsigned short)r;
}
static __device__ __forceinline__ float bflo(unsigned u){ return __uint_as_float(u << 16); }
static __device__ __forceinline__ float bfhi(unsigned u){ return __uint_as_float(u & 0xffff0000u); }
static __device__ __forceinline__ unsigned packbf(float a, float b){
    return (unsigned)f2bf(a) | ((unsigned)f2bf(b) << 16);
}

// ---------------- fused scatter + WT transpose + proj (3 blockIdx ranges) ----------------
// range [0,nsb): bucketed counting-sort scatter into PADDED ebuf (bk*BCAP + cursor)
//   -- no histogram pass needed; gcur zeroed by memset.
// range [nsb, nsb+192): WT[l][n][k] = bf16(Wc[l][k][n])
// range [nsb+192, ...): h = relu(x @ Wp + bp) -> bf16
__global__ __launch_bounds__(256) void k_scatter(const int* __restrict__ rows,
        const int* __restrict__ cols, int* __restrict__ gcur,
        unsigned* __restrict__ ebuf, int e, int nsb,
        const float* __restrict__ Wc, unsigned short* __restrict__ WT,
        const float* __restrict__ x, const float* __restrict__ Wp,
        const float* __restrict__ bp, unsigned* __restrict__ hbf, int n){
    __shared__ int lbase[NBUCK];
    __shared__ int lcur[NBUCK];
    __shared__ int gbase[NBUCK];
    __shared__ int sbuf[256];
    __shared__ unsigned sedge[SCAT_TILE];
    __shared__ unsigned char sbuck[SCAT_TILE];
    __shared__ float sW[F_IN*HD];
    __shared__ float sb[HD];
    int t = threadIdx.x;

    if (blockIdx.x >= nsb){
        int bid2 = blockIdx.x - nsb;
        if (bid2 < PREPW_BLKS){                            // WT transpose
            int i = bid2*256 + t;
            int l = i >> 14;
            int r = (i >> 7) & 127;
            int c = i & 127;
            WT[(l << 14) + c*HD + r] = f2bf(Wc[i]);
            return;
        }
        int bid = bid2 - PREPW_BLKS;                       // proj
        for (int q = t; q < F_IN*HD; q += 256) sW[q] = Wp[q];
        if (t < HD) sb[t] = bp[t];
        __syncthreads();
        int j  = t & 63;
        int ln = t >> 6;
        for (int n0 = bid*4 + ln; n0 < n; n0 += PROJ_BLKS*4){
            float a0 = sb[2*j], a1 = sb[2*j+1];
            #pragma unroll
            for (int k = 0; k < F_IN; k++){
                float xv = x[(size_t)n0*F_IN + k];
                a0 += xv * sW[k*HD + 2*j];
                a1 += xv * sW[k*HD + 2*j+1];
            }
            hbf[(size_t)n0*64 + j] = packbf(fmaxf(a0, 0.f), fmaxf(a1, 0.f));
        }
        return;
    }

    // ---- edge scatter range ----
    int i0 = blockIdx.x*SCAT_TILE + t;
    int r[16], c[16];
    if (t < NBUCK) lcur[t] = 0;
    __syncthreads();
    #pragma unroll
    for (int k = 0; k < 16; k++){
        int i = i0 + k*256;
        if (i < e){
            r[k] = rows[i]; c[k] = cols[i];
            atomicAdd(&lcur[r[k] >> 9], 1);
        } else r[k] = -1;
    }
    __syncthreads();
    int myc = (t < NBUCK) ? lcur[t] : 0;
    sbuf[t] = myc;
    __syncthreads();
    for (int d = 1; d < 256; d <<= 1){
        int tv = (t >= d) ? sbuf[t-d] : 0;
        __syncthreads();
        sbuf[t] += tv;
        __syncthreads();
    }
    if (t < NBUCK){
        lbase[t] = sbuf[t] - myc;
        lcur[t]  = sbuf[t] - myc;
        if (myc > 0) gbase[t] = t*BCAP + atomicAdd(&gcur[t], myc);
    }
    __syncthreads();
    #pragma unroll
    for (int k = 0; k < 16; k++){
        if (r[k] >= 0){
            int bk = r[k] >> 9;
            int off = atomicAdd(&lcur[bk], 1);
            sedge[off] = ((unsigned)(r[k] & 511) << 17) | (unsigned)c[k];
            sbuck[off] = (unsigned char)bk;
        }
    }
    __syncthreads();
    int tot = sbuf[255];
    for (int i = t; i < tot; i += 256){
        int bk = sbuck[i];
        ebuf[gbase[bk] + (i - lbase[bk])] = sedge[i];
    }
}

// ---------------- k_build: scan gcur -> dense bases; rowptr, dinv, coalesced colidx ----------------
// (in-block scan path validated bit-identical in R12)
__global__ __launch_bounds__(512) void k_build(const unsigned* __restrict__ ebuf,
        const int* __restrict__ gcur, int* __restrict__ rowptr,
        float* __restrict__ dinv, int* __restrict__ colidx, int n, int etot){
    __shared__ int hist[512];
    __shared__ int cur[512];
    __shared__ int colstage[BUCK_CAP];
    __shared__ int sscan[256];
    int t = threadIdx.x;
    int gval = (t < NBUCK) ? gcur[t] : 0;
    if (t < 256) sscan[t] = gval;
    __syncthreads();
    for (int d = 1; d < 256; d <<= 1){
        int tv = (t < 256 && t >= d) ? sscan[t-d] : 0;
        __syncthreads();
        if (t < 256) sscan[t] += tv;
        __syncthreads();
    }
    int b = blockIdx.x;
    int cnt = gcur[b];
    int s   = sscan[b] - cnt;          // dense base in colidx
    int sp  = b*BCAP;                  // padded base in ebuf
    int row0 = b << 9;
    int nrows = min(512, n - row0);
    if (b == 0 && t == 0) rowptr[n] = etot;
    hist[t] = 0;
    __syncthreads();
    for (int i = t; i < cnt; i += 512)
        atomicAdd(&hist[ebuf[sp + i] >> 17], 1);
    __syncthreads();
    int myc = hist[t];
    cur[t] = myc;
    __syncthreads();
    for (int d = 1; d < 512; d <<= 1){
        int tv = (t >= d) ? cur[t-d] : 0;
        __syncthreads();
        cur[t] += tv;
        __syncthreads();
    }
    int excl = cur[t] - myc;
    if (t < nrows){
        rowptr[row0 + t] = s + excl;
        dinv[row0 + t] = rsqrtf((float)(myc + 1));   // +1 self loop
    }
    cur[t] = excl;
    __syncthreads();
    for (int i = t; i < cnt; i += 512){
        unsigned v = ebuf[sp + i];
        int off = atomicAdd(&cur[v >> 17], 1);
        colstage[off] = (int)(v & 0x1ffffu);
    }
    __syncthreads();
    for (int i = t; i < cnt; i += 512)
        colidx[s + i] = colstage[i];
}

// ---------------- layer GEMM (bf16 MFMA, R11 exact) ----------------
__global__ __launch_bounds__(256) void k_gemm(const unsigned short* __restrict__ hbf,
        const unsigned short* __restrict__ WT, const float* __restrict__ dinv,
        unsigned short* __restrict__ hw, int n){
    extern __shared__ char smem[];
    unsigned short* As = (unsigned short*)smem;            // 128 x LDS_PITCH
    unsigned short* Bs = As + 128*LDS_PITCH;               // 128 x LDS_PITCH
    int tid = threadIdx.x;
    int row0 = blockIdx.x * 128;

    const uint4* h4 = (const uint4*)hbf;
    const uint4* w4 = (const uint4*)WT;
    #pragma unroll
    for (int q = tid; q < 2048; q += 256){                 // 128 rows x 16 chunks of 16B
        int r = q >> 4, c = q & 15;
        uint4 v = make_uint4(0u,0u,0u,0u);
        if (row0 + r < n) v = h4[(size_t)(row0 + r)*16 + c];
        *(uint4*)&As[r*LDS_PITCH + c*8] = v;
        *(uint4*)&Bs[r*LDS_PITCH + c*8] = w4[r*16 + c];
    }
    __syncthreads();

    int w = tid >> 6, lane = tid & 63;
    int l15 = lane & 15, quad = lane >> 4;
    f32x4 acc[2][8];
    #pragma unroll
    for (int rt = 0; rt < 2; rt++)
        #pragma unroll
        for (int ct = 0; ct < 8; ct++) acc[rt][ct] = (f32x4){0.f,0.f,0.f,0.f};

    int arow = w*32 + l15;
    #pragma unroll
    for (int kc = 0; kc < 4; kc++){
        int ko = kc*32 + quad*8;
        bf8 a0 = *(const bf8*)&As[arow*LDS_PITCH + ko];
        bf8 a1 = *(const bf8*)&As[(arow+16)*LDS_PITCH + ko];
        #pragma unroll
        for (int ct = 0; ct < 8; ct++){
            bf8 b = *(const bf8*)&Bs[(ct*16 + l15)*LDS_PITCH + ko];
            acc[0][ct] = __builtin_amdgcn_mfma_f32_16x16x32_bf16(a0, b, acc[0][ct], 0, 0, 0);
            acc[1][ct] = __builtin_amdgcn_mfma_f32_16x16x32_bf16(a1, b, acc[1][ct], 0, 0, 0);
        }
    }
    __syncthreads();                                       // done reading As/Bs

    unsigned short* CS = As;
    #pragma unroll
    for (int rt = 0; rt < 2; rt++){
        #pragma unroll
        for (int reg = 0; reg < 4; reg++){
            int rloc = w*32 + rt*16 + quad*4 + reg;
            int grow = row0 + rloc;
            float dv = (grow < n) ? dinv[grow] : 0.f;
            #pragma unroll
            for (int ct = 0; ct < 8; ct++)
                CS[rloc*CPITCH + ct*16 + l15] = f2bf(acc[rt][ct][reg] * dv);
        }
    }
    __syncthreads();

    #pragma unroll
    for (int q = tid; q < 2048; q += 256){                 // coalesced uint4 store-out
        int r = q >> 4, c = q & 15;
        if (row0 + r < n)
            *(uint4*)&hw[(size_t)(row0 + r)*HD + c*8] = *(const uint4*)&CS[r*CPITCH + c*8];
    }
}

// ---------------- aggregation + bias + BN + relu (R9/R11 exact) ----------------
__global__ __launch_bounds__(256) void k_agg(const unsigned* __restrict__ hw4,
        const int* __restrict__ rowptr, const int* __restrict__ colidx,
        const float* __restrict__ dinv, const float* __restrict__ bc,
        const float* __restrict__ bmean, const float* __restrict__ bvar,
        const float* __restrict__ bgamma, const float* __restrict__ bbeta,
        unsigned* __restrict__ houtb, int n){
    int node = blockIdx.x*4 + (threadIdx.x >> 6);
    int lane = threadIdx.x & 63;
    if (node >= n) return;
    unsigned self = hw4[(size_t)node*64 + lane];
    float ax = bflo(self), ay = bfhi(self);
    float bx = 0.f, by = 0.f;
    int s = rowptr[node], e = rowptr[node+1];
    int t = s;
    for (; t + 8 <= e; t += 8){
        int c0 = colidx[t],   c1 = colidx[t+1];
        int c2 = colidx[t+2], c3 = colidx[t+3];
        int c4 = colidx[t+4], c5 = colidx[t+5];
        int c6 = colidx[t+6], c7 = colidx[t+7];
        unsigned v0 = hw4[(size_t)c0*64 + lane];
        unsigned v1 = hw4[(size_t)c1*64 + lane];
        unsigned v2 = hw4[(size_t)c2*64 + lane];
        unsigned v3 = hw4[(size_t)c3*64 + lane];
        unsigned v4 = hw4[(size_t)c4*64 + lane];
        unsigned v5 = hw4[(size_t)c5*64 + lane];
        unsigned v6 = hw4[(size_t)c6*64 + lane];
        unsigned v7 = hw4[(size_t)c7*64 + lane];
        ax += bflo(v0); ay += bfhi(v0);
        bx += bflo(v1); by += bfhi(v1);
        ax += bflo(v2); ay += bfhi(v2);
        bx += bflo(v3); by += bfhi(v3);
        ax += bflo(v4); ay += bfhi(v4);
        bx += bflo(v5); by += bfhi(v5);
        ax += bflo(v6); ay += bfhi(v6);
        bx += bflo(v7); by += bfhi(v7);
    }
    for (; t + 4 <= e; t += 4){
        int c0 = colidx[t],   c1 = colidx[t+1];
        int c2 = colidx[t+2], c3 = colidx[t+3];
        unsigned v0 = hw4[(size_t)c0*64 + lane];
        unsigned v1 = hw4[(size_t)c1*64 + lane];
        unsigned v2 = hw4[(size_t)c2*64 + lane];
        unsigned v3 = hw4[(size_t)c3*64 + lane];
        ax += bflo(v0); ay += bfhi(v0);
        bx += bflo(v1); by += bfhi(v1);
        ax += bflo(v2); ay += bfhi(v2);
        bx += bflo(v3); by += bfhi(v3);
    }
    for (; t < e; t++){
        unsigned v = hw4[(size_t)colidx[t]*64 + lane];
        ax += bflo(v); ay += bfhi(v);
    }
    ax += bx; ay += by;
    float dv = dinv[node];
    float2 cb  = ((const float2*)bc)[lane];
    float2 cm  = ((const float2*)bmean)[lane];
    float2 cv  = ((const float2*)bvar)[lane];
    float2 cg  = ((const float2*)bgamma)[lane];
    float2 cbe = ((const float2*)bbeta)[lane];
    float rx = (ax*dv + cb.x - cm.x) * rsqrtf(cv.x + BN_EPS) * cg.x + cbe.x;
    float ry = (ay*dv + cb.y - cm.y) * rsqrtf(cv.y + BN_EPS) * cg.y + cbe.y;
    rx = fmaxf(rx, 0.f); ry = fmaxf(ry, 0.f);
    houtb[(size_t)node*64 + lane] = packbf(rx, ry);
}

// ---------------- pooling on bf16 h (fp32 accumulate, R9 exact) ----------------
__global__ void k_pool(const unsigned* __restrict__ hb, const int* __restrict__ batch,
        float* __restrict__ gsum, int* __restrict__ gmax, int n){
    int q = threadIdx.x;   // 0..63 feature pair
    int start = blockIdx.x * POOL_TILE;
    int end = min(start + POOL_TILE, n);
    if (start >= end) return;
    int cur = batch[start];
    float s0 = 0.f, s1 = 0.f, m0 = 0.f, m1 = 0.f;
    for (int i = start; i < end; i++){
        int b = batch[i];
        unsigned v = hb[(size_t)i*64 + q];
        float v0 = bflo(v), v1 = bfhi(v);
        if (b != cur){
            atomicAdd(&gsum[cur*HD + 2*q],     s0);
            atomicAdd(&gsum[cur*HD + 2*q + 1], s1);
            atomicMax(&gmax[cur*HD + 2*q],     __float_as_int(m0));
            atomicMax(&gmax[cur*HD + 2*q + 1], __float_as_int(m1));
            s0 = s1 = m0 = m1 = 0.f; cur = b;
        }
        s0 += v0; s1 += v1;
        m0 = fmaxf(m0, v0); m1 = fmaxf(m1, v1);
    }
    atomicAdd(&gsum[cur*HD + 2*q],     s0);
    atomicAdd(&gsum[cur*HD + 2*q + 1], s1);
    atomicMax(&gmax[cur*HD + 2*q],     __float_as_int(m0));
    atomicMax(&gmax[cur*HD + 2*q + 1], __float_as_int(m1));
}

// ---------------- fused head: count (binary search) + MLP1 + MLP2 ----------------
__global__ void k_head(const float* __restrict__ gsum, const int* __restrict__ gmax,
        const int* __restrict__ batch, const float* __restrict__ W1,
        const float* __restrict__ b1, const float* __restrict__ W2,
        const float* __restrict__ b2, float* __restrict__ out, int n){
    __shared__ float gv[2*HD];
    __shared__ float hid[HD];
    __shared__ int bound[2];
    int g = blockIdx.x, j = threadIdx.x;   // 128 threads
    if (j < 2){
        int target = g + j;
        int lo = 0, hi = n;
        while (lo < hi){ int mid = (lo + hi) >> 1; if (batch[mid] < target) lo = mid + 1; else hi = mid; }
        bound[j] = lo;
    }
    __syncthreads();
    float denom = (float)max(bound[1] - bound[0], 1);
    gv[j]    = gsum[g*HD+j] / denom;
    gv[HD+j] = __int_as_float(gmax[g*HD+j]);   // 0 for empty graphs (matches guard)
    __syncthreads();
    float acc = b1[j];
    #pragma unroll 8
    for (int k = 0; k < 2*HD; k++) acc += gv[k]*W1[k*HD + j];
    hid[j] = fmaxf(acc, 0.f);
    __syncthreads();
    if (j < N_CLASSES){
        float o = b2[j];
        #pragma unroll 4
        for (int k = 0; k < HD; k++) o += hid[k]*W2[k*N_CLASSES + j];
        out[g*N_CLASSES + j] = o;
    }
}

// ---------------- launch ----------------
extern "C" void kernel_launch(void* const* d_in, const int* in_sizes, int n_in,
                              void* d_out, int out_size, void* d_ws, size_t ws_size,
                              hipStream_t stream){
    const float* x   = (const float*)d_in[0];
    const int*  eidx = (const int*)d_in[1];
    const int* batch = (const int*)d_in[2];
    const float* Wp  = (const float*)d_in[3];
    const float* bp  = (const float*)d_in[4];
    const float* Wc  = (const float*)d_in[5];
    const float* bc  = (const float*)d_in[6];
    const float* bng = (const float*)d_in[7];
    const float* bnb = (const float*)d_in[8];
    const float* bnm = (const float*)d_in[9];
    const float* bnv = (const float*)d_in[10];
    const float* W1  = (const float*)d_in[11];
    const float* b1  = (const float*)d_in[12];
    const float* W2  = (const float*)d_in[13];
    const float* b2  = (const float*)d_in[14];
    float* out = (float*)d_out;

    // workspace (~68 MB). gcur|gsum|gmax contiguous -> one memset.
    char* ws = (char*)d_ws;
    size_t off = 0;
    unsigned short* h_bf  = (unsigned short*)(ws + off); off += (size_t)N_NODES*HD*2;  // 25.6 MB
    unsigned short* hw_bf = (unsigned short*)(ws + off); off += (size_t)N_NODES*HD*2;  // 25.6 MB
    unsigned short* WT = (unsigned short*)(ws + off); off += (size_t)N_LAYERS*HD*HD*2; // 98 KB
    float* dinv   = (float*)(ws + off); off += (size_t)N_NODES*4;
    int*   rowptr = (int*)  (ws + off); off += (size_t)(N_NODES+16)*4;
    int*   colidx = (int*)  (ws + off); off += (size_t)N_EDGES*4;                      // 6.4 MB
    unsigned* ebuf= (unsigned*)(ws + off); off += (size_t)NBUCK*BCAP*4;                // 7.2 MB padded
    int*   gcur   = (int*)  (ws + off); off += 1024;                                   // zeroed region start
    float* gsum   = (float*)(ws + off); off += (size_t)N_GRAPHS*HD*4;
    int*   gmax   = (int*)  (ws + off); off += (size_t)N_GRAPHS*HD*4;

    const int* rows = eidx;             // targets (aggregation index)
    const int* cols = eidx + N_EDGES;   // sources (gather index)

    // single memset: gcur + gsum + gmax (contiguous)
    hipMemsetAsync(gcur, 0, 1024 + (size_t)(N_GRAPHS*HD*2)*4, stream);

    int nsb = (N_EDGES + SCAT_TILE - 1)/SCAT_TILE;   // 391
    // fused: edge scatter (padded buckets) + WT transpose + proj
    k_scatter<<<nsb + PREPW_BLKS + PROJ_BLKS, 256, 0, stream>>>(rows, cols, gcur, ebuf,
        N_EDGES, nsb, Wc, WT, x, Wp, bp, (unsigned*)h_bf, N_NODES);
    k_build  <<<NBUCK, 512, 0, stream>>>(ebuf, gcur, rowptr, dinv, colidx, N_NODES, N_EDGES);

    int ntiles = (N_NODES + 127)/128;   // 782
    size_t shmem = (size_t)(2*128*LDS_PITCH)*2;   // 77,824 B -> 2 blocks/CU
    for (int l = 0; l < N_LAYERS; l++){
        k_gemm<<<ntiles, 256, shmem, stream>>>(h_bf, WT + (size_t)l*HD*HD, dinv, hw_bf, N_NODES);
        k_agg<<<(N_NODES+3)/4, 256, 0, stream>>>((const unsigned*)hw_bf, rowptr, colidx, dinv,
            bc + l*HD, bnm + l*HD, bnv + l*HD, bng + l*HD, bnb + l*HD,
            (unsigned*)h_bf, N_NODES);
    }

    k_pool<<<(N_NODES+POOL_TILE-1)/POOL_TILE, 64, 0, stream>>>((const unsigned*)h_bf, batch, gsum, gmax, N_NODES);
    k_head<<<N_GRAPHS, 128, 0, stream>>>(gsum, gmax, batch, W1, b1, W2, b2, out, N_NODES);
}

// Round 14
// 416.247 us; speedup vs baseline: 1.3571x; 1.0111x over previous
//
#include <hip/hip_runtime.h>

#define N_NODES   100000
#define N_EDGES   1600000
#define F_IN      10
#define HD        128
#define N_LAYERS  3
#define N_GRAPHS  256
#define N_CLASSES 25
#define BN_EPS    1e-5f
#define POOL_TILE 64
#define LDS_PITCH 152   // A/B-stage pitch (shorts): 304 B rows, 16B-aligned, 2-way conflict max
#define CPITCH    136   // C-stage pitch (shorts)

#define NBUCK     196   // ceil(100000/512) row buckets (row >> 9)
#define SCAT_TILE 4096  // edges per scatter block
#define BCAP      9216  // padded bucket capacity (mean 8192, sd ~90 -> +11 sigma)
#define BUCK_CAP  16384 // LDS colstage cap per bucket
#define PREPW_BLKS ((N_LAYERS*HD*HD)/256)   // 192
#define PROJ_BLKS 1024

typedef __attribute__((ext_vector_type(8))) short bf8;
typedef __attribute__((ext_vector_type(4))) float f32x4;

static __device__ __forceinline__ unsigned short f2bf(float f){
    unsigned u = __float_as_uint(f);
    unsigned r = (u + 0x7fffu + ((u >> 16) & 1u)) >> 16;
    return (unsigned short)r;
}
static __device__ __forceinline__ float bflo(unsigned u){ return __uint_as_float(u << 16); }
static __device__ __forceinline__ float bfhi(unsigned u){ return __uint_as_float(u & 0xffff0000u); }
static __device__ __forceinline__ unsigned packbf(float a, float b){
    return (unsigned)f2bf(a) | ((unsigned)f2bf(b) << 16);
}

// ---------------- fused scatter + WT transpose + proj (3 blockIdx ranges, R13 exact) ----------------
__global__ __launch_bounds__(256) void k_scatter(const int* __restrict__ rows,
        const int* __restrict__ cols, int* __restrict__ gcur,
        unsigned* __restrict__ ebuf, int e, int nsb,
        const float* __restrict__ Wc, unsigned short* __restrict__ WT,
        const float* __restrict__ x, const float* __restrict__ Wp,
        const float* __restrict__ bp, unsigned* __restrict__ hbf, int n){
    __shared__ int lbase[NBUCK];
    __shared__ int lcur[NBUCK];
    __shared__ int gbase[NBUCK];
    __shared__ int sbuf[256];
    __shared__ unsigned sedge[SCAT_TILE];
    __shared__ unsigned char sbuck[SCAT_TILE];
    __shared__ float sW[F_IN*HD];
    __shared__ float sb[HD];
    int t = threadIdx.x;

    if (blockIdx.x >= nsb){
        int bid2 = blockIdx.x - nsb;
        if (bid2 < PREPW_BLKS){                            // WT transpose
            int i = bid2*256 + t;
            int l = i >> 14;
            int r = (i >> 7) & 127;
            int c = i & 127;
            WT[(l << 14) + c*HD + r] = f2bf(Wc[i]);
            return;
        }
        int bid = bid2 - PREPW_BLKS;                       // proj
        for (int q = t; q < F_IN*HD; q += 256) sW[q] = Wp[q];
        if (t < HD) sb[t] = bp[t];
        __syncthreads();
        int j  = t & 63;
        int ln = t >> 6;
        for (int n0 = bid*4 + ln; n0 < n; n0 += PROJ_BLKS*4){
            float a0 = sb[2*j], a1 = sb[2*j+1];
            #pragma unroll
            for (int k = 0; k < F_IN; k++){
                float xv = x[(size_t)n0*F_IN + k];
                a0 += xv * sW[k*HD + 2*j];
                a1 += xv * sW[k*HD + 2*j+1];
            }
            hbf[(size_t)n0*64 + j] = packbf(fmaxf(a0, 0.f), fmaxf(a1, 0.f));
        }
        return;
    }

    // ---- edge scatter range ----
    int i0 = blockIdx.x*SCAT_TILE + t;
    int r[16], c[16];
    if (t < NBUCK) lcur[t] = 0;
    __syncthreads();
    #pragma unroll
    for (int k = 0; k < 16; k++){
        int i = i0 + k*256;
        if (i < e){
            r[k] = rows[i]; c[k] = cols[i];
            atomicAdd(&lcur[r[k] >> 9], 1);
        } else r[k] = -1;
    }
    __syncthreads();
    int myc = (t < NBUCK) ? lcur[t] : 0;
    sbuf[t] = myc;
    __syncthreads();
    for (int d = 1; d < 256; d <<= 1){
        int tv = (t >= d) ? sbuf[t-d] : 0;
        __syncthreads();
        sbuf[t] += tv;
        __syncthreads();
    }
    if (t < NBUCK){
        lbase[t] = sbuf[t] - myc;
        lcur[t]  = sbuf[t] - myc;
        if (myc > 0) gbase[t] = t*BCAP + atomicAdd(&gcur[t], myc);
    }
    __syncthreads();
    #pragma unroll
    for (int k = 0; k < 16; k++){
        if (r[k] >= 0){
            int bk = r[k] >> 9;
            int off = atomicAdd(&lcur[bk], 1);
            sedge[off] = ((unsigned)(r[k] & 511) << 17) | (unsigned)c[k];
            sbuck[off] = (unsigned char)bk;
        }
    }
    __syncthreads();
    int tot = sbuf[255];
    for (int i = t; i < tot; i += 256){
        int bk = sbuck[i];
        ebuf[gbase[bk] + (i - lbase[bk])] = sedge[i];
    }
}

// ---------------- k_build (R13 exact) ----------------
__global__ __launch_bounds__(512) void k_build(const unsigned* __restrict__ ebuf,
        const int* __restrict__ gcur, int* __restrict__ rowptr,
        float* __restrict__ dinv, int* __restrict__ colidx, int n, int etot){
    __shared__ int hist[512];
    __shared__ int cur[512];
    __shared__ int colstage[BUCK_CAP];
    __shared__ int sscan[256];
    int t = threadIdx.x;
    int gval = (t < NBUCK) ? gcur[t] : 0;
    if (t < 256) sscan[t] = gval;
    __syncthreads();
    for (int d = 1; d < 256; d <<= 1){
        int tv = (t < 256 && t >= d) ? sscan[t-d] : 0;
        __syncthreads();
        if (t < 256) sscan[t] += tv;
        __syncthreads();
    }
    int b = blockIdx.x;
    int cnt = gcur[b];
    int s   = sscan[b] - cnt;          // dense base in colidx
    int sp  = b*BCAP;                  // padded base in ebuf
    int row0 = b << 9;
    int nrows = min(512, n - row0);
    if (b == 0 && t == 0) rowptr[n] = etot;
    hist[t] = 0;
    __syncthreads();
    for (int i = t; i < cnt; i += 512)
        atomicAdd(&hist[ebuf[sp + i] >> 17], 1);
    __syncthreads();
    int myc = hist[t];
    cur[t] = myc;
    __syncthreads();
    for (int d = 1; d < 512; d <<= 1){
        int tv = (t >= d) ? cur[t-d] : 0;
        __syncthreads();
        cur[t] += tv;
        __syncthreads();
    }
    int excl = cur[t] - myc;
    if (t < nrows){
        rowptr[row0 + t] = s + excl;
        dinv[row0 + t] = rsqrtf((float)(myc + 1));   // +1 self loop
    }
    cur[t] = excl;
    __syncthreads();
    for (int i = t; i < cnt; i += 512){
        unsigned v = ebuf[sp + i];
        int off = atomicAdd(&cur[v >> 17], 1);
        colstage[off] = (int)(v & 0x1ffffu);
    }
    __syncthreads();
    for (int i = t; i < cnt; i += 512)
        colidx[s + i] = colstage[i];
}

// ---------------- layer GEMM (bf16 MFMA): 512 threads, 128-row tile ----------------
// R14: same LDS layout/tile/math as R13, but 8 waves/block -> 16 waves/CU
// (2 LDS-limited blocks). Staging is the bottleneck (~2800 cyc/block vs ~400
// compute); doubling resident waves doubles outstanding-load capacity.
// Each wave now covers 16 rows (1x8 MFMA tiles) instead of 32 -> identical
// fragment reads and MFMA values, redistributed -> bit-identical output.
__global__ __launch_bounds__(512) void k_gemm(const unsigned short* __restrict__ hbf,
        const unsigned short* __restrict__ WT, const float* __restrict__ dinv,
        unsigned short* __restrict__ hw, int n){
    extern __shared__ char smem[];
    unsigned short* As = (unsigned short*)smem;            // 128 x LDS_PITCH
    unsigned short* Bs = As + 128*LDS_PITCH;               // 128 x LDS_PITCH
    int tid = threadIdx.x;
    int row0 = blockIdx.x * 128;

    const uint4* h4 = (const uint4*)hbf;
    const uint4* w4 = (const uint4*)WT;
    #pragma unroll
    for (int q = tid; q < 2048; q += 512){                 // 128 rows x 16 chunks of 16B
        int r = q >> 4, c = q & 15;
        uint4 v = make_uint4(0u,0u,0u,0u);
        if (row0 + r < n) v = h4[(size_t)(row0 + r)*16 + c];
        *(uint4*)&As[r*LDS_PITCH + c*8] = v;
        *(uint4*)&Bs[r*LDS_PITCH + c*8] = w4[r*16 + c];
    }
    __syncthreads();

    int w = tid >> 6, lane = tid & 63;                     // 8 waves
    int l15 = lane & 15, quad = lane >> 4;
    f32x4 acc[8];
    #pragma unroll
    for (int ct = 0; ct < 8; ct++) acc[ct] = (f32x4){0.f,0.f,0.f,0.f};

    int arow = w*16 + l15;
    #pragma unroll
    for (int kc = 0; kc < 4; kc++){
        int ko = kc*32 + quad*8;
        bf8 a = *(const bf8*)&As[arow*LDS_PITCH + ko];
        #pragma unroll
        for (int ct = 0; ct < 8; ct++){
            bf8 b = *(const bf8*)&Bs[(ct*16 + l15)*LDS_PITCH + ko];
            acc[ct] = __builtin_amdgcn_mfma_f32_16x16x32_bf16(a, b, acc[ct], 0, 0, 0);
        }
    }
    __syncthreads();                                       // done reading As/Bs

    unsigned short* CS = As;
    #pragma unroll
    for (int reg = 0; reg < 4; reg++){
        int rloc = w*16 + quad*4 + reg;
        int grow = row0 + rloc;
        float dv = (grow < n) ? dinv[grow] : 0.f;
        #pragma unroll
        for (int ct = 0; ct < 8; ct++)
            CS[rloc*CPITCH + ct*16 + l15] = f2bf(acc[ct][reg] * dv);
    }
    __syncthreads();

    #pragma unroll
    for (int q = tid; q < 2048; q += 512){                 // coalesced uint4 store-out
        int r = q >> 4, c = q & 15;
        if (row0 + r < n)
            *(uint4*)&hw[(size_t)(row0 + r)*HD + c*8] = *(const uint4*)&CS[r*CPITCH + c*8];
    }
}

// ---------------- aggregation + bias + BN + relu (R9/R13 exact) ----------------
__global__ __launch_bounds__(256) void k_agg(const unsigned* __restrict__ hw4,
        const int* __restrict__ rowptr, const int* __restrict__ colidx,
        const float* __restrict__ dinv, const float* __restrict__ bc,
        const float* __restrict__ bmean, const float* __restrict__ bvar,
        const float* __restrict__ bgamma, const float* __restrict__ bbeta,
        unsigned* __restrict__ houtb, int n){
    int node = blockIdx.x*4 + (threadIdx.x >> 6);
    int lane = threadIdx.x & 63;
    if (node >= n) return;
    unsigned self = hw4[(size_t)node*64 + lane];
    float ax = bflo(self), ay = bfhi(self);
    float bx = 0.f, by = 0.f;
    int s = rowptr[node], e = rowptr[node+1];
    int t = s;
    for (; t + 8 <= e; t += 8){
        int c0 = colidx[t],   c1 = colidx[t+1];
        int c2 = colidx[t+2], c3 = colidx[t+3];
        int c4 = colidx[t+4], c5 = colidx[t+5];
        int c6 = colidx[t+6], c7 = colidx[t+7];
        unsigned v0 = hw4[(size_t)c0*64 + lane];
        unsigned v1 = hw4[(size_t)c1*64 + lane];
        unsigned v2 = hw4[(size_t)c2*64 + lane];
        unsigned v3 = hw4[(size_t)c3*64 + lane];
        unsigned v4 = hw4[(size_t)c4*64 + lane];
        unsigned v5 = hw4[(size_t)c5*64 + lane];
        unsigned v6 = hw4[(size_t)c6*64 + lane];
        unsigned v7 = hw4[(size_t)c7*64 + lane];
        ax += bflo(v0); ay += bfhi(v0);
        bx += bflo(v1); by += bfhi(v1);
        ax += bflo(v2); ay += bfhi(v2);
        bx += bflo(v3); by += bfhi(v3);
        ax += bflo(v4); ay += bfhi(v4);
        bx += bflo(v5); by += bfhi(v5);
        ax += bflo(v6); ay += bfhi(v6);
        bx += bflo(v7); by += bfhi(v7);
    }
    for (; t + 4 <= e; t += 4){
        int c0 = colidx[t],   c1 = colidx[t+1];
        int c2 = colidx[t+2], c3 = colidx[t+3];
        unsigned v0 = hw4[(size_t)c0*64 + lane];
        unsigned v1 = hw4[(size_t)c1*64 + lane];
        unsigned v2 = hw4[(size_t)c2*64 + lane];
        unsigned v3 = hw4[(size_t)c3*64 + lane];
        ax += bflo(v0); ay += bfhi(v0);
        bx += bflo(v1); by += bfhi(v1);
        ax += bflo(v2); ay += bfhi(v2);
        bx += bflo(v3); by += bfhi(v3);
    }
    for (; t < e; t++){
        unsigned v = hw4[(size_t)colidx[t]*64 + lane];
        ax += bflo(v); ay += bfhi(v);
    }
    ax += bx; ay += by;
    float dv = dinv[node];
    float2 cb  = ((const float2*)bc)[lane];
    float2 cm  = ((const float2*)bmean)[lane];
    float2 cv  = ((const float2*)bvar)[lane];
    float2 cg  = ((const float2*)bgamma)[lane];
    float2 cbe = ((const float2*)bbeta)[lane];
    float rx = (ax*dv + cb.x - cm.x) * rsqrtf(cv.x + BN_EPS) * cg.x + cbe.x;
    float ry = (ay*dv + cb.y - cm.y) * rsqrtf(cv.y + BN_EPS) * cg.y + cbe.y;
    rx = fmaxf(rx, 0.f); ry = fmaxf(ry, 0.f);
    houtb[(size_t)node*64 + lane] = packbf(rx, ry);
}

// ---------------- pooling on bf16 h (fp32 accumulate, R9 exact) ----------------
__global__ void k_pool(const unsigned* __restrict__ hb, const int* __restrict__ batch,
        float* __restrict__ gsum, int* __restrict__ gmax, int n){
    int q = threadIdx.x;   // 0..63 feature pair
    int start = blockIdx.x * POOL_TILE;
    int end = min(start + POOL_TILE, n);
    if (start >= end) return;
    int cur = batch[start];
    float s0 = 0.f, s1 = 0.f, m0 = 0.f, m1 = 0.f;
    for (int i = start; i < end; i++){
        int b = batch[i];
        unsigned v = hb[(size_t)i*64 + q];
        float v0 = bflo(v), v1 = bfhi(v);
        if (b != cur){
            atomicAdd(&gsum[cur*HD + 2*q],     s0);
            atomicAdd(&gsum[cur*HD + 2*q + 1], s1);
            atomicMax(&gmax[cur*HD + 2*q],     __float_as_int(m0));
            atomicMax(&gmax[cur*HD + 2*q + 1], __float_as_int(m1));
            s0 = s1 = m0 = m1 = 0.f; cur = b;
        }
        s0 += v0; s1 += v1;
        m0 = fmaxf(m0, v0); m1 = fmaxf(m1, v1);
    }
    atomicAdd(&gsum[cur*HD + 2*q],     s0);
    atomicAdd(&gsum[cur*HD + 2*q + 1], s1);
    atomicMax(&gmax[cur*HD + 2*q],     __float_as_int(m0));
    atomicMax(&gmax[cur*HD + 2*q + 1], __float_as_int(m1));
}

// ---------------- fused head: count (binary search) + MLP1 + MLP2 ----------------
__global__ void k_head(const float* __restrict__ gsum, const int* __restrict__ gmax,
        const int* __restrict__ batch, const float* __restrict__ W1,
        const float* __restrict__ b1, const float* __restrict__ W2,
        const float* __restrict__ b2, float* __restrict__ out, int n){
    __shared__ float gv[2*HD];
    __shared__ float hid[HD];
    __shared__ int bound[2];
    int g = blockIdx.x, j = threadIdx.x;   // 128 threads
    if (j < 2){
        int target = g + j;
        int lo = 0, hi = n;
        while (lo < hi){ int mid = (lo + hi) >> 1; if (batch[mid] < target) lo = mid + 1; else hi = mid; }
        bound[j] = lo;
    }
    __syncthreads();
    float denom = (float)max(bound[1] - bound[0], 1);
    gv[j]    = gsum[g*HD+j] / denom;
    gv[HD+j] = __int_as_float(gmax[g*HD+j]);   // 0 for empty graphs (matches guard)
    __syncthreads();
    float acc = b1[j];
    #pragma unroll 8
    for (int k = 0; k < 2*HD; k++) acc += gv[k]*W1[k*HD + j];
    hid[j] = fmaxf(acc, 0.f);
    __syncthreads();
    if (j < N_CLASSES){
        float o = b2[j];
        #pragma unroll 4
        for (int k = 0; k < HD; k++) o += hid[k]*W2[k*N_CLASSES + j];
        out[g*N_CLASSES + j] = o;
    }
}

// ---------------- launch ----------------
extern "C" void kernel_launch(void* const* d_in, const int* in_sizes, int n_in,
                              void* d_out, int out_size, void* d_ws, size_t ws_size,
                              hipStream_t stream){
    const float* x   = (const float*)d_in[0];
    const int*  eidx = (const int*)d_in[1];
    const int* batch = (const int*)d_in[2];
    const float* Wp  = (const float*)d_in[3];
    const float* bp  = (const float*)d_in[4];
    const float* Wc  = (const float*)d_in[5];
    const float* bc  = (const float*)d_in[6];
    const float* bng = (const float*)d_in[7];
    const float* bnb = (const float*)d_in[8];
    const float* bnm = (const float*)d_in[9];
    const float* bnv = (const float*)d_in[10];
    const float* W1  = (const float*)d_in[11];
    const float* b1  = (const float*)d_in[12];
    const float* W2  = (const float*)d_in[13];
    const float* b2  = (const float*)d_in[14];
    float* out = (float*)d_out;

    // workspace (~68 MB). gcur|gsum|gmax contiguous -> one memset.
    char* ws = (char*)d_ws;
    size_t off = 0;
    unsigned short* h_bf  = (unsigned short*)(ws + off); off += (size_t)N_NODES*HD*2;  // 25.6 MB
    unsigned short* hw_bf = (unsigned short*)(ws + off); off += (size_t)N_NODES*HD*2;  // 25.6 MB
    unsigned short* WT = (unsigned short*)(ws + off); off += (size_t)N_LAYERS*HD*HD*2; // 98 KB
    float* dinv   = (float*)(ws + off); off += (size_t)N_NODES*4;
    int*   rowptr = (int*)  (ws + off); off += (size_t)(N_NODES+16)*4;
    int*   colidx = (int*)  (ws + off); off += (size_t)N_EDGES*4;                      // 6.4 MB
    unsigned* ebuf= (unsigned*)(ws + off); off += (size_t)NBUCK*BCAP*4;                // 7.2 MB padded
    int*   gcur   = (int*)  (ws + off); off += 1024;                                   // zeroed region start
    float* gsum   = (float*)(ws + off); off += (size_t)N_GRAPHS*HD*4;
    int*   gmax   = (int*)  (ws + off); off += (size_t)N_GRAPHS*HD*4;

    const int* rows = eidx;             // targets (aggregation index)
    const int* cols = eidx + N_EDGES;   // sources (gather index)

    // single memset: gcur + gsum + gmax (contiguous)
    hipMemsetAsync(gcur, 0, 1024 + (size_t)(N_GRAPHS*HD*2)*4, stream);

    int nsb = (N_EDGES + SCAT_TILE - 1)/SCAT_TILE;   // 391
    k_scatter<<<nsb + PREPW_BLKS + PROJ_BLKS, 256, 0, stream>>>(rows, cols, gcur, ebuf,
        N_EDGES, nsb, Wc, WT, x, Wp, bp, (unsigned*)h_bf, N_NODES);
    k_build  <<<NBUCK, 512, 0, stream>>>(ebuf, gcur, rowptr, dinv, colidx, N_NODES, N_EDGES);

    int ntiles = (N_NODES + 127)/128;   // 782
    size_t shmem = (size_t)(2*128*LDS_PITCH)*2;   // 77,824 B -> 2 blocks/CU, now 16 waves/CU
    for (int l = 0; l < N_LAYERS; l++){
        k_gemm<<<ntiles, 512, shmem, stream>>>(h_bf, WT + (size_t)l*HD*HD, dinv, hw_bf, N_NODES);
        k_agg<<<(N_NODES+3)/4, 256, 0, stream>>>((const unsigned*)hw_bf, rowptr, colidx, dinv,
            bc + l*HD, bnm + l*HD, bnv + l*HD, bng + l*HD, bnb + l*HD,
            (unsigned*)h_bf, N_NODES);
    }

    k_pool<<<(N_NODES+POOL_TILE-1)/POOL_TILE, 64, 0, stream>>>((const unsigned*)h_bf, batch, gsum, gmax, N_NODES);
    k_head<<<N_GRAPHS, 128, 0, stream>>>(gsum, gmax, batch, W1, b1, W2, b2, out, N_NODES);
}